// Round 1
// baseline (920.893 us; speedup 1.0000x reference)
//
#include <hip/hip_runtime.h>
#include <cmath>

#define GAMMA 0.9865f
#define BATCH 8
#define SEQ 4000
#define NCHUNK 800
#define CSUP 25
#define GSUP 32
#define ROWS_PER_G 125   // 5*CSUP

// ---------------- Kernel A: dst[m][n] = sum_k x[m][k]*W[k][n], M=32000,N=256,K=256
// BM=BN=BK=64, 256 threads (16x16), 4x4 micro-tile.
__global__ __launch_bounds__(256) void qkv_gemm(
    const float* __restrict__ xq, const float* __restrict__ xk, const float* __restrict__ xv,
    const float* __restrict__ Wq, const float* __restrict__ Wk, const float* __restrict__ Wv,
    float* __restrict__ Qb, float* __restrict__ Kb, float* __restrict__ Vb) {
    const float* x; const float* W; float* dst;
    if (blockIdx.z == 0) { x = xq; W = Wq; dst = Qb; }
    else if (blockIdx.z == 1) { x = xk; W = Wk; dst = Kb; }
    else { x = xv; W = Wv; dst = Vb; }
    __shared__ float As[64][68];   // As[k][m] (transposed)
    __shared__ float Bs[64][68];   // Bs[k][n]
    int t = threadIdx.x;
    int tx = t & 15, ty = t >> 4;
    int row0 = blockIdx.x * 64;
    int col0 = blockIdx.y * 64;
    float acc[4][4] = {};
    for (int kt = 0; kt < 4; ++kt) {
        int k0 = kt * 64;
#pragma unroll
        for (int i = 0; i < 16; ++i) {
            int idx = t + i * 256;
            int m = idx >> 6, k = idx & 63;
            As[k][m] = x[(size_t)(row0 + m) * 256 + k0 + k];
        }
#pragma unroll
        for (int i = 0; i < 16; ++i) {
            int idx = t + i * 256;
            int k = idx >> 6, n = idx & 63;
            Bs[k][n] = W[(size_t)(k0 + k) * 256 + col0 + n];
        }
        __syncthreads();
#pragma unroll
        for (int k = 0; k < 64; ++k) {
            float4 a = *(const float4*)&As[k][ty * 4];
            float4 bvv = *(const float4*)&Bs[k][tx * 4];
            float av[4] = {a.x, a.y, a.z, a.w};
            float bv[4] = {bvv.x, bvv.y, bvv.z, bvv.w};
#pragma unroll
            for (int i = 0; i < 4; ++i)
#pragma unroll
                for (int j = 0; j < 4; ++j) acc[i][j] += av[i] * bv[j];
        }
        __syncthreads();
    }
#pragma unroll
    for (int i = 0; i < 4; ++i)
#pragma unroll
        for (int j = 0; j < 4; ++j)
            dst[(size_t)(row0 + ty * 4 + i) * 256 + col0 + tx * 4 + j] = acc[i][j];
}

// ---------------- Kernel B1: W_g[d][e] = sum_{r=0..124} K[gr+r][d] * V[gr+r][e] * alpha(r)
// grid: (16 tiles of 64x64, g=32, b=8)
__global__ __launch_bounds__(256) void chunk_states(
    const float* __restrict__ Kb, const float* __restrict__ Vb, float* __restrict__ Sbuf) {
    int g = blockIdx.y, b = blockIdx.z;
    int tile = blockIdx.x;
    int d0 = (tile >> 2) * 64, e0 = (tile & 3) * 64;
    int t = threadIdx.x, tx = t & 15, ty = t >> 4;
    __shared__ float Ks[25][68];
    __shared__ float Vs[25][68];
    float acc[4][4] = {};
    int base_row = b * SEQ + g * ROWS_PER_G;
    for (int kt = 0; kt < 5; ++kt) {
        for (int i = 0; i < 7; ++i) {
            int idx = t + i * 256;
            if (idx < 1600) {
                int r = idx >> 6, dd = idx & 63;
                int rl = kt * 25 + r;
                Ks[r][dd] = Kb[(size_t)(base_row + rl) * 256 + d0 + dd];
                int mloc = rl / 5;
                float alpha = powf(GAMMA, (float)(124 - 6 * mloc - 25 * g));
                Vs[r][dd] = Vb[(size_t)(base_row + rl) * 256 + e0 + dd] * alpha;
            }
        }
        __syncthreads();
#pragma unroll
        for (int r = 0; r < 25; ++r) {
            float4 kv = *(const float4*)&Ks[r][ty * 4];
            float4 vv = *(const float4*)&Vs[r][tx * 4];
            float ka[4] = {kv.x, kv.y, kv.z, kv.w};
            float va[4] = {vv.x, vv.y, vv.z, vv.w};
#pragma unroll
            for (int i = 0; i < 4; ++i)
#pragma unroll
                for (int j = 0; j < 4; ++j) acc[i][j] += ka[i] * va[j];
        }
        __syncthreads();
    }
    size_t base = ((size_t)(g * 8 + b)) << 16;
#pragma unroll
    for (int i = 0; i < 4; ++i)
#pragma unroll
        for (int j = 0; j < 4; ++j)
            Sbuf[base + (size_t)(d0 + ty * 4 + i) * 256 + e0 + tx * 4 + j] = acc[i][j];
}

// ---------------- Kernel B2: in-place exclusive scan over g: S_g = W_g + gB^C * S_{g-1}
__global__ void state_scan(float* __restrict__ Sbuf) {
    int t = blockIdx.x * blockDim.x + threadIdx.x;
    if (t >= BATCH * 65536) return;
    int b = t >> 16;
    int de = t & 65535;
    const float gBC = powf(GAMMA, 125.0f);
    float s = 0.f;
    for (int g = 0; g < GSUP; ++g) {
        size_t idx = (((size_t)(g * 8 + b)) << 16) + de;
        float w = Sbuf[idx];
        Sbuf[idx] = s;
        s = w + gBC * s;
    }
}

// ---------------- Kernel C1: cross term per (g,b). Writes out (=).
// out rows: 125 (chunks gC..gC+C-1), cols 256 in 2 passes of 128.
__global__ __launch_bounds__(256) void cross_kernel(
    const float* __restrict__ Qb, const float* __restrict__ Kb, const float* __restrict__ Vb,
    const float* __restrict__ Sbuf, float* __restrict__ out) {
    int g = blockIdx.x, b = blockIdx.y;
    int t = threadIdx.x, tx = t & 15, ty = t >> 4;
    __shared__ float Ph[128][65];
    __shared__ float QsT[16][132];
    __shared__ float TsT[16][132];
    __shared__ float KsT[16][68];
    int kvbase = b * SEQ + g * ROWS_PER_G;
    size_t sbase = ((size_t)(g * 8 + b)) << 16;

    for (int ep = 0; ep < 2; ++ep) {
        int e0 = ep * 128;
        float acc[8][8] = {};
        // ---- S-part: acc[r][e] = sum_d Q'[r][d] * Sprev[d][e]
        for (int dt = 0; dt < 16; ++dt) {
#pragma unroll
            for (int i = 0; i < 8; ++i) {
                int idx = t + i * 256;
                int rp = idx >> 4, dd = idx & 15;
                int qr = g * ROWS_PER_G + rp + 5;
                float v = 0.f;
                if (rp < 125 && qr < SEQ)
                    v = Qb[(size_t)(b * SEQ + qr) * 256 + dt * 16 + dd];
                QsT[dd][rp] = v;
            }
#pragma unroll
            for (int i = 0; i < 8; ++i) {
                int idx = t + i * 256;
                int dd = idx >> 7, ee = idx & 127;
                TsT[dd][ee] = Sbuf[sbase + (size_t)(dt * 16 + dd) * 256 + e0 + ee];
            }
            __syncthreads();
#pragma unroll
            for (int dd = 0; dd < 16; ++dd) {
                float4 a0 = *(const float4*)&QsT[dd][ty * 8];
                float4 a1 = *(const float4*)&QsT[dd][ty * 8 + 4];
                float4 b0 = *(const float4*)&TsT[dd][tx * 8];
                float4 b1 = *(const float4*)&TsT[dd][tx * 8 + 4];
                float av[8] = {a0.x, a0.y, a0.z, a0.w, a1.x, a1.y, a1.z, a1.w};
                float bv[8] = {b0.x, b0.y, b0.z, b0.w, b1.x, b1.y, b1.z, b1.w};
#pragma unroll
                for (int i = 0; i < 8; ++i)
#pragma unroll
                    for (int j = 0; j < 8; ++j) acc[i][j] += av[i] * bv[j];
            }
            __syncthreads();
        }
        // rowscale = gamma^(25g + 6rc + 7), zero for last chunk overall
#pragma unroll
        for (int i = 0; i < 8; ++i) {
            int rp = ty * 8 + i;
            int rc = rp / 5;
            float rs = 0.f;
            if (rp < 125 && !(g == GSUP - 1 && rc == CSUP - 1))
                rs = powf(GAMMA, (float)(25 * g + 6 * rc + 7));
#pragma unroll
            for (int j = 0; j < 8; ++j) acc[i][j] *= rs;
        }
        // ---- local P parts, 2 column halves of 64
        for (int ch = 0; ch < 2; ++ch) {
            float pacc[8][4] = {};
            for (int dt = 0; dt < 16; ++dt) {
#pragma unroll
                for (int i = 0; i < 8; ++i) {
                    int idx = t + i * 256;
                    int rp = idx >> 4, dd = idx & 15;
                    int qr = g * ROWS_PER_G + rp + 5;
                    float v = 0.f;
                    if (rp < 125 && qr < SEQ)
                        v = Qb[(size_t)(b * SEQ + qr) * 256 + dt * 16 + dd];
                    QsT[dd][rp] = v;
                }
#pragma unroll
                for (int i = 0; i < 4; ++i) {
                    int idx = t + i * 256;
                    int c2 = idx >> 4, dd = idx & 15;
                    int cp = ch * 64 + c2;
                    float v = (cp < 125) ? Kb[(size_t)(kvbase + cp) * 256 + dt * 16 + dd] : 0.f;
                    KsT[dd][c2] = v;
                }
                __syncthreads();
#pragma unroll
                for (int dd = 0; dd < 16; ++dd) {
                    float4 a0 = *(const float4*)&QsT[dd][ty * 8];
                    float4 a1 = *(const float4*)&QsT[dd][ty * 8 + 4];
                    float4 kb = *(const float4*)&KsT[dd][tx * 4];
                    float av[8] = {a0.x, a0.y, a0.z, a0.w, a1.x, a1.y, a1.z, a1.w};
                    float kv[4] = {kb.x, kb.y, kb.z, kb.w};
#pragma unroll
                    for (int i = 0; i < 8; ++i)
#pragma unroll
                        for (int j = 0; j < 4; ++j) pacc[i][j] += av[i] * kv[j];
                }
                __syncthreads();
            }
            // decay mask + store P
#pragma unroll
            for (int i = 0; i < 8; ++i) {
                int rp = ty * 8 + i;
                int rc = rp / 5;
#pragma unroll
                for (int j = 0; j < 4; ++j) {
                    int c2 = tx * 4 + j;
                    int cp = ch * 64 + c2;
                    int cc = cp / 5;
                    float w = 0.f;
                    if (rp < 125 && cp < 125 && cc <= rc && !(g == GSUP - 1 && rc == CSUP - 1))
                        w = powf(GAMMA, (float)(6 * (rc - cc + 1)));
                    Ph[rp][c2] = pacc[i][j] * w;
                }
            }
            __syncthreads();
            // acc += P @ V_local
            for (int ct = 0; ct < 4; ++ct) {
#pragma unroll
                for (int i = 0; i < 8; ++i) {
                    int idx = t + i * 256;
                    int cc = idx >> 7, ee = idx & 127;
                    int cp = ch * 64 + ct * 16 + cc;
                    float v = (cp < 125) ? Vb[(size_t)(kvbase + cp) * 256 + e0 + ee] : 0.f;
                    TsT[cc][ee] = v;
                }
                __syncthreads();
#pragma unroll
                for (int cc = 0; cc < 16; ++cc) {
                    float4 b0 = *(const float4*)&TsT[cc][tx * 8];
                    float4 b1 = *(const float4*)&TsT[cc][tx * 8 + 4];
                    float bv[8] = {b0.x, b0.y, b0.z, b0.w, b1.x, b1.y, b1.z, b1.w};
                    float pa[8];
#pragma unroll
                    for (int i = 0; i < 8; ++i) pa[i] = Ph[ty * 8 + i][ct * 16 + cc];
#pragma unroll
                    for (int i = 0; i < 8; ++i)
#pragma unroll
                        for (int j = 0; j < 8; ++j) acc[i][j] += pa[i] * bv[j];
                }
                __syncthreads();
            }
        }
        // write
#pragma unroll
        for (int i = 0; i < 8; ++i) {
            int rp = ty * 8 + i;
            if (rp < 125) {
                size_t orow = (size_t)(b * SEQ + g * ROWS_PER_G + rp) * 256 + e0;
#pragma unroll
                for (int j = 0; j < 8; ++j) out[orow + tx * 8 + j] = acc[i][j];
            }
        }
        __syncthreads();
    }
}

// ---------------- Kernel D: intra term, out += (Q_j K_j^T * L) V_j. grid (800, 8)
__global__ __launch_bounds__(256) void intra_kernel(
    const float* __restrict__ Qb, const float* __restrict__ Kb, const float* __restrict__ Vb,
    float* __restrict__ out) {
    int j = blockIdx.x, b = blockIdx.y;
    int t = threadIdx.x;
    __shared__ float sc[5][5];
    int base = b * SEQ + j * 5;
    if (t < 25) sc[t / 5][t % 5] = 0.f;
    __syncthreads();
    if (t < 200) {
        int pair = t >> 3;
        int p = pair / 5, q = pair % 5;
        if (q <= p) {
            int ds = (t & 7) * 32;
            const float* qrow = Qb + (size_t)(base + p) * 256 + ds;
            const float* krow = Kb + (size_t)(base + q) * 256 + ds;
            float s = 0.f;
#pragma unroll
            for (int d = 0; d < 32; ++d) s += qrow[d] * krow[d];
            atomicAdd(&sc[p][q], s);
        }
    }
    __syncthreads();
    int e = t;
#pragma unroll
    for (int p = 0; p < 5; ++p) {
        float acc2 = 0.f;
        for (int q = 0; q <= p; ++q)
            acc2 += sc[p][q] * powf(GAMMA, (float)(q - p)) * Vb[(size_t)(base + q) * 256 + e];
        out[(size_t)(base + p) * 256 + e] += acc2;
    }
}

extern "C" void kernel_launch(void* const* d_in, const int* in_sizes, int n_in,
                              void* d_out, int out_size, void* d_ws, size_t ws_size,
                              hipStream_t stream) {
    const float* xq = (const float*)d_in[0];
    const float* xk = (const float*)d_in[1];
    const float* xv = (const float*)d_in[2];
    const float* Wq = (const float*)d_in[3];
    const float* Wk = (const float*)d_in[4];
    const float* Wv = (const float*)d_in[5];
    float* out = (float*)d_out;

    float* Qb = (float*)d_ws;
    float* Kb = Qb + (size_t)SEQ * BATCH * 256;
    float* Vb = Kb + (size_t)SEQ * BATCH * 256;
    float* Sbuf = Vb + (size_t)SEQ * BATCH * 256;   // [g][b][256][256]

    qkv_gemm<<<dim3(500, 4, 3), 256, 0, stream>>>(xq, xk, xv, Wq, Wk, Wv, Qb, Kb, Vb);
    chunk_states<<<dim3(16, 32, 8), 256, 0, stream>>>(Kb, Vb, Sbuf);
    state_scan<<<dim3(2048), 256, 0, stream>>>(Sbuf);
    cross_kernel<<<dim3(32, 8), 256, 0, stream>>>(Qb, Kb, Vb, Sbuf, out);
    intra_kernel<<<dim3(800, 8), 256, 0, stream>>>(Qb, Kb, Vb, out);
}

// Round 2
// 322.063 us; speedup vs baseline: 2.8594x; 2.8594x over previous
//
#include <hip/hip_runtime.h>
#include <cmath>

#define GAMMA 0.9865f
#define L2G   -0.01960905f   // log2(0.9865)
#define BATCH 8
#define SEQ   4000
#define CSUP  25
#define GSUP  32
#define RPG   125            // rows per superchunk = 5*CSUP

typedef _Float16 half8 __attribute__((ext_vector_type(8)));
typedef _Float16 half4 __attribute__((ext_vector_type(4)));
typedef float    floatx4 __attribute__((ext_vector_type(4)));

__device__ __forceinline__ float gpow(float e) { return exp2f(e * L2G); }  // GAMMA^e

// ---------------- Kernel 0: transpose+convert W -> Wt[mat][n][k] fp16
__global__ __launch_bounds__(256) void wt_convert(
    const float* __restrict__ Wq, const float* __restrict__ Wk, const float* __restrict__ Wv,
    _Float16* __restrict__ Wt) {
    int t = blockIdx.x * 256 + threadIdx.x;           // 3*65536
    int mat = t >> 16, rem = t & 65535;
    int n = rem >> 8, k = rem & 255;
    const float* W = (mat == 0) ? Wq : (mat == 1) ? Wk : Wv;
    Wt[(size_t)mat * 65536 + n * 256 + k] = (_Float16)W[k * 256 + n];
}

// ---------------- Kernel 1: QKV projection, fp16 MFMA.  dst = x @ W  (M=32000,N=256,K=256)
// block: 128 rows x 256 cols, 256 threads (4 waves), wave -> 4 n-tiles x 8 m-tiles.
__global__ __launch_bounds__(256, 2) void qkv_gemm_f16(
    const float* __restrict__ xq, const float* __restrict__ xk, const float* __restrict__ xv,
    const _Float16* __restrict__ WtAll,
    _Float16* __restrict__ Qb, _Float16* __restrict__ Kb, _Float16* __restrict__ Vb) {
    int op = blockIdx.y;
    const float* x = (op == 0) ? xq : (op == 1) ? xk : xv;
    const _Float16* Wt = WtAll + (size_t)op * 65536;
    _Float16* dst = (op == 0) ? Qb : (op == 1) ? Kb : Vb;

    __shared__ _Float16 Xs[128][40];
    __shared__ _Float16 WsT[256][40];

    int t = threadIdx.x;
    int lane = t & 63, wave = t >> 6;
    int ln = lane & 15, q8 = (lane >> 4) << 3, q4 = (lane >> 4) << 2;
    int row0 = blockIdx.x * 128;

    floatx4 acc[8][4] = {};

    for (int dt = 0; dt < 8; ++dt) {
        int k0 = dt * 32;
#pragma unroll
        for (int i = 0; i < 4; ++i) {          // Xs: 1024 float4 loads -> fp16
            int idx = t + i * 256;
            int m = idx >> 3, kk = (idx & 7) << 2;
            floatx4 v = *(const floatx4*)&x[(size_t)(row0 + m) * 256 + k0 + kk];
            half4 h; h[0] = (_Float16)v[0]; h[1] = (_Float16)v[1];
            h[2] = (_Float16)v[2]; h[3] = (_Float16)v[3];
            *(half4*)&Xs[m][kk] = h;
        }
#pragma unroll
        for (int i = 0; i < 4; ++i) {          // WsT: 1024 half8
            int idx = t + i * 256;
            int n = idx >> 2, kk = (idx & 3) << 3;
            *(half8*)&WsT[n][kk] = *(const half8*)&Wt[n * 256 + k0 + kk];
        }
        __syncthreads();
        half8 af[8];
#pragma unroll
        for (int mi = 0; mi < 8; ++mi) af[mi] = *(const half8*)&Xs[mi * 16 + ln][q8];
#pragma unroll
        for (int ni = 0; ni < 4; ++ni) {
            half8 bf = *(const half8*)&WsT[(wave * 4 + ni) * 16 + ln][q8];
#pragma unroll
            for (int mi = 0; mi < 8; ++mi)
                acc[mi][ni] = __builtin_amdgcn_mfma_f32_16x16x32_f16(af[mi], bf, acc[mi][ni], 0, 0, 0);
        }
        __syncthreads();
    }
#pragma unroll
    for (int mi = 0; mi < 8; ++mi)
#pragma unroll
        for (int ni = 0; ni < 4; ++ni)
#pragma unroll
            for (int r = 0; r < 4; ++r) {
                int row = row0 + mi * 16 + q4 + r;
                int col = (wave * 4 + ni) * 16 + ln;
                dst[(size_t)row * 256 + col] = (_Float16)acc[mi][ni][r];
            }
}

// ---------------- Kernel 2: W'_g^T[e][d] = sum_r V[r][e]*alpha'(r) * K[r][d],  alpha' = g^(149-6*mloc)
__global__ __launch_bounds__(256) void chunk_states(
    const _Float16* __restrict__ Kb, const _Float16* __restrict__ Vb, float* __restrict__ Sbuf) {
    int g = blockIdx.y, b = blockIdx.z;
    int tile = blockIdx.x;
    int d0 = (tile >> 2) * 64, e0 = (tile & 3) * 64;
    int t = threadIdx.x, tx = t & 15, ty = t >> 4;
    __shared__ float Ks[25][68];
    __shared__ float Vs[25][68];
    float acc[4][4] = {};
    int base_row = b * SEQ + g * RPG;
    for (int kt = 0; kt < 5; ++kt) {
        for (int i = 0; i < 7; ++i) {
            int idx = t + i * 256;
            if (idx < 1600) {
                int r = idx >> 6, dd = idx & 63;
                int rl = kt * 25 + r;
                Ks[r][dd] = (float)Kb[(size_t)(base_row + rl) * 256 + d0 + dd];
                int mloc = rl / 5;
                float alpha = gpow((float)(149 - 6 * mloc));
                Vs[r][dd] = (float)Vb[(size_t)(base_row + rl) * 256 + e0 + dd] * alpha;
            }
        }
        __syncthreads();
#pragma unroll
        for (int r = 0; r < 25; ++r) {
            float4 vv = *(const float4*)&Vs[r][ty * 4];   // e-index by ty
            float4 kv = *(const float4*)&Ks[r][tx * 4];   // d-index by tx
            float va[4] = {vv.x, vv.y, vv.z, vv.w};
            float ka[4] = {kv.x, kv.y, kv.z, kv.w};
#pragma unroll
            for (int i = 0; i < 4; ++i)
#pragma unroll
                for (int j = 0; j < 4; ++j) acc[i][j] += va[i] * ka[j];
        }
        __syncthreads();
    }
    size_t base = ((size_t)(g * 8 + b)) << 16;   // layout [e][d]
#pragma unroll
    for (int i = 0; i < 4; ++i) {
        float4 v; v.x = acc[i][0]; v.y = acc[i][1]; v.z = acc[i][2]; v.w = acc[i][3];
        *(float4*)&Sbuf[base + (size_t)(e0 + ty * 4 + i) * 256 + d0 + tx * 4] = v;
    }
}

// ---------------- Kernel 3: exclusive scan over g: store S'_g (fp16), S'_g = W'_{g-1} + g^150 S'_{g-1}
__global__ __launch_bounds__(256) void state_scan(
    const float* __restrict__ Sbuf, _Float16* __restrict__ SprevT) {
    int t = blockIdx.x * 256 + threadIdx.x;   // 8*65536
    int b = t >> 16, idx = t & 65535;
    const float gF = gpow(150.0f);
    float s = 0.f;
    for (int g = 0; g < GSUP; ++g) {
        size_t o = (((size_t)(g * 8 + b)) << 16) + idx;
        SprevT[o] = (_Float16)s;
        s = Sbuf[o] + gF * s;
    }
}

// ---------------- Kernel 4: cross term, fp16 MFMA.
// grid (4 e-quarters, 32 g, 8 b); block: out tile 128(rows,pad from 125) x 64(e).
// out = rowscale*(Q' @ S'_g) + (mask o (Q' @ K_loc^T)) @ V_loc
__global__ __launch_bounds__(256, 2) void cross_f16(
    const _Float16* __restrict__ Qb, const _Float16* __restrict__ Kb,
    const _Float16* __restrict__ Vb, const _Float16* __restrict__ SprevT,
    float* __restrict__ out) {
    int eq = blockIdx.x, g = blockIdx.y, b = blockIdx.z;
    int e0 = eq * 64;
    int t = threadIdx.x;
    int lane = t & 63, wave = t >> 6;
    int ln = lane & 15, q8 = (lane >> 4) << 3, q4 = (lane >> 4) << 2;
    int m4 = (wave >> 1) * 4;      // 4 m-tiles (16 rows each) per wave
    int c4 = (wave & 1) * 4;       // 4 cp-tiles for the P accumulator
    int e2 = (wave & 1) * 2;       // 2 e-tiles for the main accumulator

    // LDS layout (59 KB): Qs[128][40] | Ks[128][40] | Ss[64][40] | Ps[128][136]; VsT[64][136] overlaps Qs/Ks
    __shared__ __align__(16) char smem[60416];
    _Float16* QsB  = (_Float16*)smem;              // [128][40]
    _Float16* KsB  = (_Float16*)(smem + 10240);    // [128][40]
    _Float16* VsTB = (_Float16*)smem;              // [64][136] (after K-loop)
    _Float16* SsB  = (_Float16*)(smem + 20480);    // [64][40]
    _Float16* PsB  = (_Float16*)(smem + 25600);    // [128][136]
#define QS(m_, k_)  QsB[(m_) * 40 + (k_)]
#define KS(m_, k_)  KsB[(m_) * 40 + (k_)]
#define SS(m_, k_)  SsB[(m_) * 40 + (k_)]
#define PS(m_, k_)  PsB[(m_) * 136 + (k_)]
#define VST(m_, k_) VsTB[(m_) * 136 + (k_)]

    size_t kvbase = (size_t)b * SEQ + g * RPG;
    size_t sb = ((size_t)(g * 8 + b)) << 16;

    floatx4 pacc[4][4] = {};
    floatx4 acc[4][2] = {};

    // ---- fused K-loop over d: P = Q'@K^T and QS = Q'@S' simultaneously
    for (int dt = 0; dt < 8; ++dt) {
        int d0 = dt * 32;
#pragma unroll
        for (int i = 0; i < 2; ++i) {          // Qs: 512 half8
            int idx = t + i * 256;
            int m = idx >> 2, kk = (idx & 3) << 3;
            int qr = g * RPG + 5 + m;
            half8 v = {};
            if (m < 125 && qr < SEQ) v = *(const half8*)&Qb[((size_t)b * SEQ + qr) * 256 + d0 + kk];
            *(half8*)&QS(m, kk) = v;
        }
#pragma unroll
        for (int i = 0; i < 2; ++i) {          // Ks: 512 half8
            int idx = t + i * 256;
            int cp = idx >> 2, kk = (idx & 3) << 3;
            half8 v = {};
            if (cp < 125) v = *(const half8*)&Kb[(kvbase + cp) * 256 + d0 + kk];
            *(half8*)&KS(cp, kk) = v;
        }
        {                                       // Ss: 256 half8
            int ee = t >> 2, kk = (t & 3) << 3;
            *(half8*)&SS(ee, kk) = *(const half8*)&SprevT[sb + (size_t)(e0 + ee) * 256 + d0 + kk];
        }
        __syncthreads();
        half8 af[4];
#pragma unroll
        for (int mi = 0; mi < 4; ++mi) af[mi] = *(const half8*)&QS((m4 + mi) * 16 + ln, q8);
#pragma unroll
        for (int ci = 0; ci < 4; ++ci) {
            half8 bf = *(const half8*)&KS((c4 + ci) * 16 + ln, q8);
#pragma unroll
            for (int mi = 0; mi < 4; ++mi)
                pacc[mi][ci] = __builtin_amdgcn_mfma_f32_16x16x32_f16(af[mi], bf, pacc[mi][ci], 0, 0, 0);
        }
#pragma unroll
        for (int ei = 0; ei < 2; ++ei) {
            half8 bf = *(const half8*)&SS((e2 + ei) * 16 + ln, q8);
#pragma unroll
            for (int mi = 0; mi < 4; ++mi)
                acc[mi][ei] = __builtin_amdgcn_mfma_f32_16x16x32_f16(af[mi], bf, acc[mi][ei], 0, 0, 0);
        }
        __syncthreads();
    }

    // ---- rowscale on the S-part: gamma^(6rc+7), zero past row 124 / last chunk overall
#pragma unroll
    for (int mi = 0; mi < 4; ++mi)
#pragma unroll
        for (int r = 0; r < 4; ++r) {
            int rp = (m4 + mi) * 16 + q4 + r;
            int rc = rp / 5;
            float rs = 0.f;
            if (rp < 125 && !(g == GSUP - 1 && rc == CSUP - 1)) rs = gpow((float)(6 * rc + 7));
            acc[mi][0][r] *= rs;
            acc[mi][1][r] *= rs;
        }

    // ---- stage VsT (overlaps dead Qs/Ks) and write masked P (fp16)
#pragma unroll
    for (int i = 0; i < 32; ++i) {
        int idx = t + i * 256;
        int cp = idx >> 6, ee = idx & 63;
        _Float16 v = (_Float16)0.f;
        if (cp < 125) v = Vb[(kvbase + cp) * 256 + e0 + ee];
        VST(ee, cp) = v;
    }
#pragma unroll
    for (int mi = 0; mi < 4; ++mi)
#pragma unroll
        for (int ci = 0; ci < 4; ++ci)
#pragma unroll
            for (int r = 0; r < 4; ++r) {
                int rp = (m4 + mi) * 16 + q4 + r;
                int cp = (c4 + ci) * 16 + ln;
                int rc = rp / 5, cc = cp / 5;
                float w = 0.f;
                if (rp < 125 && cp < 125 && cc <= rc && !(g == GSUP - 1 && rc == CSUP - 1))
                    w = gpow((float)(6 * (rc - cc + 1)));
                PS(rp, cp) = (_Float16)(pacc[mi][ci][r] * w);
            }
    __syncthreads();

    // ---- PV: acc += P @ V_loc  (all operands in LDS)
#pragma unroll
    for (int ct = 0; ct < 4; ++ct) {
        int cp0 = ct * 32;
        half8 paf[4];
#pragma unroll
        for (int mi = 0; mi < 4; ++mi) paf[mi] = *(const half8*)&PS((m4 + mi) * 16 + ln, cp0 + q8);
#pragma unroll
        for (int ei = 0; ei < 2; ++ei) {
            half8 bv = *(const half8*)&VST((e2 + ei) * 16 + ln, cp0 + q8);
#pragma unroll
            for (int mi = 0; mi < 4; ++mi)
                acc[mi][ei] = __builtin_amdgcn_mfma_f32_16x16x32_f16(paf[mi], bv, acc[mi][ei], 0, 0, 0);
        }
    }

    // ---- epilogue
#pragma unroll
    for (int mi = 0; mi < 4; ++mi)
#pragma unroll
        for (int r = 0; r < 4; ++r) {
            int rp = (m4 + mi) * 16 + q4 + r;
            if (rp < 125) {
                size_t orow = ((size_t)b * SEQ + g * RPG + rp) * 256;
#pragma unroll
                for (int ei = 0; ei < 2; ++ei)
                    out[orow + e0 + (e2 + ei) * 16 + ln] = acc[mi][ei][r];
            }
        }
}

// ---------------- Kernel 5: intra term, out += (Q_j K_j^T * L) V_j. grid (800, 8)
__global__ __launch_bounds__(256) void intra_kernel(
    const _Float16* __restrict__ Qb, const _Float16* __restrict__ Kb,
    const _Float16* __restrict__ Vb, float* __restrict__ out) {
    int j = blockIdx.x, b = blockIdx.y;
    int t = threadIdx.x;
    __shared__ float sc[5][5];
    int base = b * SEQ + j * 5;
    if (t < 25) sc[t / 5][t % 5] = 0.f;
    __syncthreads();
    if (t < 200) {
        int pair = t >> 3;
        int p = pair / 5, qq = pair % 5;
        if (qq <= p) {
            int ds = (t & 7) * 32;
            const _Float16* qrow = Qb + (size_t)(base + p) * 256 + ds;
            const _Float16* krow = Kb + (size_t)(base + qq) * 256 + ds;
            float s = 0.f;
#pragma unroll
            for (int d = 0; d < 32; ++d) s += (float)qrow[d] * (float)krow[d];
            atomicAdd(&sc[p][qq], s);
        }
    }
    __syncthreads();
    int e = t;
#pragma unroll
    for (int p = 0; p < 5; ++p) {
        float acc2 = 0.f;
        for (int qq = 0; qq <= p; ++qq)
            acc2 += sc[p][qq] * gpow((float)(qq - p)) * (float)Vb[(size_t)(base + qq) * 256 + e];
        out[(size_t)(base + p) * 256 + e] += acc2;
    }
}

extern "C" void kernel_launch(void* const* d_in, const int* in_sizes, int n_in,
                              void* d_out, int out_size, void* d_ws, size_t ws_size,
                              hipStream_t stream) {
    const float* xq = (const float*)d_in[0];
    const float* xk = (const float*)d_in[1];
    const float* xv = (const float*)d_in[2];
    const float* Wq = (const float*)d_in[3];
    const float* Wk = (const float*)d_in[4];
    const float* Wv = (const float*)d_in[5];
    float* out = (float*)d_out;

    const size_t NELEM = (size_t)SEQ * BATCH * 256;   // 8,192,000
    _Float16* Qb = (_Float16*)d_ws;
    _Float16* Kb = Qb + NELEM;
    _Float16* Vb = Kb + NELEM;
    _Float16* Wt = Vb + NELEM;                        // 196,608 halves
    float* Sbuf = (float*)(Wt + 196608);              // [g][b][e][d] fp32, 67.1 MB
    _Float16* SprevT = (_Float16*)(Sbuf + (size_t)GSUP * BATCH * 65536);  // fp16, 33.5 MB

    wt_convert<<<dim3(768), 256, 0, stream>>>(Wq, Wk, Wv, Wt);
    qkv_gemm_f16<<<dim3(250, 3), 256, 0, stream>>>(xq, xk, xv, Wt, Qb, Kb, Vb);
    chunk_states<<<dim3(16, 32, 8), 256, 0, stream>>>(Kb, Vb, Sbuf);
    state_scan<<<dim3(2048), 256, 0, stream>>>(Sbuf, SprevT);
    cross_f16<<<dim3(4, 32, 8), 256, 0, stream>>>(Qb, Kb, Vb, SprevT, out);
    intra_kernel<<<dim3(800, 8), 256, 0, stream>>>(Qb, Kb, Vb, out);
}

// Round 3
// 275.072 us; speedup vs baseline: 3.3478x; 1.1708x over previous
//
#include <hip/hip_runtime.h>
#include <cmath>

#define GAMMA 0.9865f
#define L2G   -0.01960905f   // log2(0.9865)
#define BATCH 8
#define SEQ   4000
#define CSUP  25
#define GSUP  32
#define RPG   125            // rows per superchunk = 5*CSUP

typedef _Float16 half8 __attribute__((ext_vector_type(8)));
typedef _Float16 half4 __attribute__((ext_vector_type(4)));
typedef float    floatx4 __attribute__((ext_vector_type(4)));

__device__ __forceinline__ float gpow(float e) { return exp2f(e * L2G); }  // GAMMA^e

// ---------------- Kernel 0: transpose+convert W -> Wt[mat][n][k] fp16
__global__ __launch_bounds__(256) void wt_convert(
    const float* __restrict__ Wq, const float* __restrict__ Wk, const float* __restrict__ Wv,
    _Float16* __restrict__ Wt) {
    int t = blockIdx.x * 256 + threadIdx.x;           // 3*65536
    int mat = t >> 16, rem = t & 65535;
    int n = rem >> 8, k = rem & 255;
    const float* W = (mat == 0) ? Wq : (mat == 1) ? Wk : Wv;
    Wt[(size_t)mat * 65536 + n * 256 + k] = (_Float16)W[k * 256 + n];
}

// ---------------- Kernel 1: QKV projection, fp16 MFMA.  dst = x @ W  (M=32000,N=256,K=256)
__global__ __launch_bounds__(256, 2) void qkv_gemm_f16(
    const float* __restrict__ xq, const float* __restrict__ xk, const float* __restrict__ xv,
    const _Float16* __restrict__ WtAll,
    _Float16* __restrict__ Qb, _Float16* __restrict__ Kb, _Float16* __restrict__ Vb) {
    int op = blockIdx.y;
    const float* x = (op == 0) ? xq : (op == 1) ? xk : xv;
    const _Float16* Wt = WtAll + (size_t)op * 65536;
    _Float16* dst = (op == 0) ? Qb : (op == 1) ? Kb : Vb;

    __shared__ _Float16 Xs[128][40];
    __shared__ _Float16 WsT[256][40];

    int t = threadIdx.x;
    int lane = t & 63, wave = t >> 6;
    int ln = lane & 15, q8 = (lane >> 4) << 3, q4 = (lane >> 4) << 2;
    int row0 = blockIdx.x * 128;

    floatx4 acc[8][4] = {};

    for (int dt = 0; dt < 8; ++dt) {
        int k0 = dt * 32;
#pragma unroll
        for (int i = 0; i < 4; ++i) {
            int idx = t + i * 256;
            int m = idx >> 3, kk = (idx & 7) << 2;
            floatx4 v = *(const floatx4*)&x[(size_t)(row0 + m) * 256 + k0 + kk];
            half4 h; h[0] = (_Float16)v[0]; h[1] = (_Float16)v[1];
            h[2] = (_Float16)v[2]; h[3] = (_Float16)v[3];
            *(half4*)&Xs[m][kk] = h;
        }
#pragma unroll
        for (int i = 0; i < 4; ++i) {
            int idx = t + i * 256;
            int n = idx >> 2, kk = (idx & 3) << 3;
            *(half8*)&WsT[n][kk] = *(const half8*)&Wt[n * 256 + k0 + kk];
        }
        __syncthreads();
        half8 af[8];
#pragma unroll
        for (int mi = 0; mi < 8; ++mi) af[mi] = *(const half8*)&Xs[mi * 16 + ln][q8];
#pragma unroll
        for (int ni = 0; ni < 4; ++ni) {
            half8 bf = *(const half8*)&WsT[(wave * 4 + ni) * 16 + ln][q8];
#pragma unroll
            for (int mi = 0; mi < 8; ++mi)
                acc[mi][ni] = __builtin_amdgcn_mfma_f32_16x16x32_f16(af[mi], bf, acc[mi][ni], 0, 0, 0);
        }
        __syncthreads();
    }
#pragma unroll
    for (int mi = 0; mi < 8; ++mi)
#pragma unroll
        for (int ni = 0; ni < 4; ++ni)
#pragma unroll
            for (int r = 0; r < 4; ++r) {
                int row = row0 + mi * 16 + q4 + r;
                int col = (wave * 4 + ni) * 16 + ln;
                dst[(size_t)row * 256 + col] = (_Float16)acc[mi][ni][r];
            }
}

// ---------------- Kernel 2: chunk states via MFMA.
// Wh[g][b][e][d] (fp16) = sum_r V[r][e]*alpha'(r) * K[r][d], alpha' = g^(149-6*mloc).
// grid (2 e-halves, 32 g, 8 b); block 128e x 256d; wave w -> 8 m-tiles(e) x 4 n-tiles(d).
__global__ __launch_bounds__(256, 2) void chunk_states_mfma(
    const _Float16* __restrict__ Kb, const _Float16* __restrict__ Vb,
    _Float16* __restrict__ Wh) {
    int eh = blockIdx.x, g = blockIdx.y, b = blockIdx.z;
    int t = threadIdx.x, lane = t & 63, wave = t >> 6;
    int ln = lane & 15, q8 = (lane >> 4) << 3, q4 = (lane >> 4) << 2;
    __shared__ __align__(16) _Float16 Vs[32 * 136];
    __shared__ __align__(16) _Float16 Ks[32 * 264];
    size_t base_row = (size_t)b * SEQ + g * RPG;
    floatx4 acc[8][4] = {};
    for (int kt = 0; kt < 4; ++kt) {
        int r0 = kt * 32;
#pragma unroll
        for (int i = 0; i < 2; ++i) {          // Vs[r][e] with alpha
            int idx = t + i * 256;
            int r = idx >> 4, e8 = (idx & 15) << 3;
            half8 v = {};
            if (r0 + r < RPG) {
                v = *(const half8*)&Vb[(base_row + r0 + r) * 256 + eh * 128 + e8];
                int mloc = (r0 + r) / 5;
                float a = gpow((float)(149 - 6 * mloc));
#pragma unroll
                for (int z = 0; z < 8; ++z) v[z] = (_Float16)((float)v[z] * a);
            }
            *(half8*)&Vs[r * 136 + e8] = v;
        }
#pragma unroll
        for (int i = 0; i < 4; ++i) {          // Ks[r][d]
            int idx = t + i * 256;
            int r = idx >> 5, d8 = (idx & 31) << 3;
            half8 v = {};
            if (r0 + r < RPG) v = *(const half8*)&Kb[(base_row + r0 + r) * 256 + d8];
            *(half8*)&Ks[r * 264 + d8] = v;
        }
        __syncthreads();
        half8 Af[8], Bf[4];
#pragma unroll
        for (int mi = 0; mi < 8; ++mi)
#pragma unroll
            for (int j = 0; j < 8; ++j) Af[mi][j] = Vs[(q8 + j) * 136 + mi * 16 + ln];
#pragma unroll
        for (int ni = 0; ni < 4; ++ni)
#pragma unroll
            for (int j = 0; j < 8; ++j) Bf[ni][j] = Ks[(q8 + j) * 264 + wave * 64 + ni * 16 + ln];
#pragma unroll
        for (int mi = 0; mi < 8; ++mi)
#pragma unroll
            for (int ni = 0; ni < 4; ++ni)
                acc[mi][ni] = __builtin_amdgcn_mfma_f32_16x16x32_f16(Af[mi], Bf[ni], acc[mi][ni], 0, 0, 0);
        __syncthreads();
    }
    size_t ob = ((size_t)(g * 8 + b)) << 16;
#pragma unroll
    for (int mi = 0; mi < 8; ++mi)
#pragma unroll
        for (int ni = 0; ni < 4; ++ni)
#pragma unroll
            for (int r = 0; r < 4; ++r) {
                int e = eh * 128 + mi * 16 + q4 + r;
                int d = wave * 64 + ni * 16 + ln;
                Wh[ob + (size_t)e * 256 + d] = (_Float16)acc[mi][ni][r];
            }
}

// ---------------- Kernel 3: exclusive scan over g (fp16 in/out, fp32 accum)
__global__ __launch_bounds__(256) void state_scan(
    const _Float16* __restrict__ Wh, _Float16* __restrict__ SprevT) {
    int t = blockIdx.x * 256 + threadIdx.x;   // 65536 threads
    int b = t >> 13;
    int idx = (t & 8191) << 3;                // 8 consecutive halves
    const float gF = gpow(150.0f);
    float s[8] = {};
    for (int g = 0; g < GSUP; ++g) {
        size_t o = (((size_t)(g * 8 + b)) << 16) + idx;
        half8 w = *(const half8*)&Wh[o];
        half8 sv;
#pragma unroll
        for (int z = 0; z < 8; ++z) { sv[z] = (_Float16)s[z]; s[z] = (float)w[z] + gF * s[z]; }
        *(half8*)&SprevT[o] = sv;
    }
}

// ---------------- Kernel 4: intra score matrices, pre-scaled by gamma^(q-p).
// scw[b][j][p][q] = (Q[j*5+p] . K[j*5+q]) * gamma^(q-p) for q<=p.  grid (200, 8)
__global__ __launch_bounds__(256) void intra_sc(
    const _Float16* __restrict__ Qb, const _Float16* __restrict__ Kb, float* __restrict__ scw) {
    int b = blockIdx.y;
    int j = blockIdx.x * 4 + (threadIdx.x >> 6);
    int lane = threadIdx.x & 63;
    size_t base = ((size_t)b * SEQ + j * 5) * 256 + lane * 4;
    half4 qv[5], kv[5];
#pragma unroll
    for (int p = 0; p < 5; ++p) {
        qv[p] = *(const half4*)&Qb[base + p * 256];
        kv[p] = *(const half4*)&Kb[base + p * 256];
    }
#pragma unroll
    for (int p = 0; p < 5; ++p)
#pragma unroll
        for (int q = 0; q <= p; ++q) {
            float s = 0.f;
#pragma unroll
            for (int z = 0; z < 4; ++z) s += (float)qv[p][z] * (float)kv[q][z];
#pragma unroll
            for (int off = 32; off; off >>= 1) s += __shfl_xor(s, off, 64);
            if (lane == 0) scw[((size_t)b * 800 + j) * 25 + p * 5 + q] = s * gpow((float)(q - p));
        }
}

// ---------------- Kernel 5: cross + fused intra epilogue.
// grid (4 e-quarters, 32 g, 8 b); out = rowscale*(Q'@S') + (mask o (Q'@K^T))@V + intra
__global__ __launch_bounds__(256, 2) void cross_f16(
    const _Float16* __restrict__ Qb, const _Float16* __restrict__ Kb,
    const _Float16* __restrict__ Vb, const _Float16* __restrict__ SprevT,
    const float* __restrict__ scw, float* __restrict__ out) {
    int eq = blockIdx.x, g = blockIdx.y, b = blockIdx.z;
    int e0 = eq * 64;
    int t = threadIdx.x;
    int lane = t & 63, wave = t >> 6;
    int ln = lane & 15, q8 = (lane >> 4) << 3, q4 = (lane >> 4) << 2;
    int m4 = (wave >> 1) * 4;
    int c4 = (wave & 1) * 4;
    int e2 = (wave & 1) * 2;

    __shared__ __align__(16) char smem[60416];
    _Float16* QsB  = (_Float16*)smem;              // [128][40]
    _Float16* KsB  = (_Float16*)(smem + 10240);    // [128][40]
    _Float16* VsTB = (_Float16*)smem;              // [64][136] (after K-loop)
    _Float16* SsB  = (_Float16*)(smem + 20480);    // [64][40]
    _Float16* PsB  = (_Float16*)(smem + 25600);    // [128][136]
#define QS(m_, k_)  QsB[(m_) * 40 + (k_)]
#define KS(m_, k_)  KsB[(m_) * 40 + (k_)]
#define SS(m_, k_)  SsB[(m_) * 40 + (k_)]
#define PS(m_, k_)  PsB[(m_) * 136 + (k_)]
#define VST(m_, k_) VsTB[(m_) * 136 + (k_)]

    size_t kvbase = (size_t)b * SEQ + g * RPG;
    size_t sb = ((size_t)(g * 8 + b)) << 16;

    floatx4 pacc[4][4] = {};
    floatx4 acc[4][2] = {};

    for (int dt = 0; dt < 8; ++dt) {
        int d0 = dt * 32;
#pragma unroll
        for (int i = 0; i < 2; ++i) {
            int idx = t + i * 256;
            int m = idx >> 2, kk = (idx & 3) << 3;
            int qr = g * RPG + 5 + m;
            half8 v = {};
            if (m < 125 && qr < SEQ) v = *(const half8*)&Qb[((size_t)b * SEQ + qr) * 256 + d0 + kk];
            *(half8*)&QS(m, kk) = v;
        }
#pragma unroll
        for (int i = 0; i < 2; ++i) {
            int idx = t + i * 256;
            int cp = idx >> 2, kk = (idx & 3) << 3;
            half8 v = {};
            if (cp < 125) v = *(const half8*)&Kb[(kvbase + cp) * 256 + d0 + kk];
            *(half8*)&KS(cp, kk) = v;
        }
        {
            int ee = t >> 2, kk = (t & 3) << 3;
            *(half8*)&SS(ee, kk) = *(const half8*)&SprevT[sb + (size_t)(e0 + ee) * 256 + d0 + kk];
        }
        __syncthreads();
        half8 af[4];
#pragma unroll
        for (int mi = 0; mi < 4; ++mi) af[mi] = *(const half8*)&QS((m4 + mi) * 16 + ln, q8);
#pragma unroll
        for (int ci = 0; ci < 4; ++ci) {
            half8 bf = *(const half8*)&KS((c4 + ci) * 16 + ln, q8);
#pragma unroll
            for (int mi = 0; mi < 4; ++mi)
                pacc[mi][ci] = __builtin_amdgcn_mfma_f32_16x16x32_f16(af[mi], bf, pacc[mi][ci], 0, 0, 0);
        }
#pragma unroll
        for (int ei = 0; ei < 2; ++ei) {
            half8 bf = *(const half8*)&SS((e2 + ei) * 16 + ln, q8);
#pragma unroll
            for (int mi = 0; mi < 4; ++mi)
                acc[mi][ei] = __builtin_amdgcn_mfma_f32_16x16x32_f16(af[mi], bf, acc[mi][ei], 0, 0, 0);
        }
        __syncthreads();
    }

#pragma unroll
    for (int mi = 0; mi < 4; ++mi)
#pragma unroll
        for (int r = 0; r < 4; ++r) {
            int rp = (m4 + mi) * 16 + q4 + r;
            int rc = rp / 5;
            float rs = 0.f;
            if (rp < 125 && !(g == GSUP - 1 && rc == CSUP - 1)) rs = gpow((float)(6 * rc + 7));
            acc[mi][0][r] *= rs;
            acc[mi][1][r] *= rs;
        }

#pragma unroll
    for (int i = 0; i < 32; ++i) {
        int idx = t + i * 256;
        int cp = idx >> 6, ee = idx & 63;
        _Float16 v = (_Float16)0.f;
        if (cp < 125) v = Vb[(kvbase + cp) * 256 + e0 + ee];
        VST(ee, cp) = v;
    }
#pragma unroll
    for (int mi = 0; mi < 4; ++mi)
#pragma unroll
        for (int ci = 0; ci < 4; ++ci)
#pragma unroll
            for (int r = 0; r < 4; ++r) {
                int rp = (m4 + mi) * 16 + q4 + r;
                int cp = (c4 + ci) * 16 + ln;
                int rc = rp / 5, cc = cp / 5;
                float w = 0.f;
                if (rp < 125 && cp < 125 && cc <= rc && !(g == GSUP - 1 && rc == CSUP - 1))
                    w = gpow((float)(6 * (rc - cc + 1)));
                PS(rp, cp) = (_Float16)(pacc[mi][ci][r] * w);
            }
    __syncthreads();

#pragma unroll
    for (int ct = 0; ct < 4; ++ct) {
        int cp0 = ct * 32;
        half8 paf[4];
#pragma unroll
        for (int mi = 0; mi < 4; ++mi) paf[mi] = *(const half8*)&PS((m4 + mi) * 16 + ln, cp0 + q8);
#pragma unroll
        for (int ei = 0; ei < 2; ++ei) {
            half8 bv = *(const half8*)&VST((e2 + ei) * 16 + ln, cp0 + q8);
#pragma unroll
            for (int mi = 0; mi < 4; ++mi)
                acc[mi][ei] = __builtin_amdgcn_mfma_f32_16x16x32_f16(paf[mi], bv, acc[mi][ei], 0, 0, 0);
        }
    }

    // ---- epilogue: add intra term from scw + VST, single fp32 store
#pragma unroll
    for (int mi = 0; mi < 4; ++mi)
#pragma unroll
        for (int r = 0; r < 4; ++r) {
            int rp = (m4 + mi) * 16 + q4 + r;
            if (rp < 125) {
                int rc = rp / 5, pp = rp - rc * 5;
                const float* srow = scw + ((size_t)b * 800 + g * 25 + rc) * 25 + pp * 5;
                float a0 = acc[mi][0][r], a1 = acc[mi][1][r];
                for (int q = 0; q <= pp; ++q) {
                    float s = srow[q];
                    a0 += s * (float)VST(e2 * 16 + ln, rc * 5 + q);
                    a1 += s * (float)VST((e2 + 1) * 16 + ln, rc * 5 + q);
                }
                size_t orow = ((size_t)b * SEQ + g * RPG + rp) * 256;
                out[orow + e0 + e2 * 16 + ln] = a0;
                out[orow + e0 + (e2 + 1) * 16 + ln] = a1;
            }
        }
}

extern "C" void kernel_launch(void* const* d_in, const int* in_sizes, int n_in,
                              void* d_out, int out_size, void* d_ws, size_t ws_size,
                              hipStream_t stream) {
    const float* xq = (const float*)d_in[0];
    const float* xk = (const float*)d_in[1];
    const float* xv = (const float*)d_in[2];
    const float* Wq = (const float*)d_in[3];
    const float* Wk = (const float*)d_in[4];
    const float* Wv = (const float*)d_in[5];
    float* out = (float*)d_out;

    const size_t NELEM = (size_t)SEQ * BATCH * 256;   // 8,192,000
    _Float16* Qb = (_Float16*)d_ws;
    _Float16* Kb = Qb + NELEM;
    _Float16* Vb = Kb + NELEM;
    _Float16* Wt = Vb + NELEM;                              // 196,608 halves
    _Float16* Wh = Wt + 196608;                             // [g][b][e][d] fp16, 33.5 MB
    _Float16* SprevT = Wh + (size_t)GSUP * BATCH * 65536;   // fp16, 33.5 MB
    float* scw = (float*)(SprevT + (size_t)GSUP * BATCH * 65536);  // 640 KB

    wt_convert<<<dim3(768), 256, 0, stream>>>(Wq, Wk, Wv, Wt);
    qkv_gemm_f16<<<dim3(250, 3), 256, 0, stream>>>(xq, xk, xv, Wt, Qb, Kb, Vb);
    chunk_states_mfma<<<dim3(2, 32, 8), 256, 0, stream>>>(Kb, Vb, Wh);
    state_scan<<<dim3(256), 256, 0, stream>>>(Wh, SprevT);
    intra_sc<<<dim3(200, 8), 256, 0, stream>>>(Qb, Kb, scw);
    cross_f16<<<dim3(4, 32, 8), 256, 0, stream>>>(Qb, Kb, Vb, SprevT, scw, out);
}